// Round 7
// baseline (1819.456 us; speedup 1.0000x reference)
//
#include <hip/hip_runtime.h>
#include <hip/hip_bf16.h>

#define D 64
#define NEG_SLOPE 0.2f
#define EPS 1e-12f
#define CB 8                 // 256 rows per coarse bucket
#define CROWS (1 << CB)
#define NBC_MAX 1024         // supports N <= 262144
#define TILE_E 8192

// ===========================================================================
// CSR build: tile-ranked scatter into coarse buckets (write-amp-free),
// then per-bucket counting sort by local row -> split cols[]/vals[] CSR.
// ===========================================================================

__global__ __launch_bounds__(256) void hist_coarse(const int* __restrict__ rows,
                                                   int* __restrict__ bcount,
                                                   int nnz, int nbc) {
  __shared__ int h[NBC_MAX];
  for (int i = threadIdx.x; i < nbc; i += 256) h[i] = 0;
  __syncthreads();
  for (int k = blockIdx.x * 256 + threadIdx.x; k < nnz; k += gridDim.x * 256)
    atomicAdd(&h[rows[k] >> CB], 1);
  __syncthreads();
  for (int i = threadIdx.x; i < nbc; i += 256)
    if (h[i]) atomicAdd(&bcount[i], h[i]);
}

#define SCAN_E2 4
__global__ __launch_bounds__(256) void scan_buckets(
    const int* __restrict__ bcount, int* __restrict__ bbase,
    int* __restrict__ bcursor, int nbc, int nnz, int* __restrict__ row_ptr,
    int N) {
  __shared__ int sums[256];
  int base = threadIdx.x * SCAN_E2;
  int c[SCAN_E2];
  int tsum = 0;
#pragma unroll
  for (int i = 0; i < SCAN_E2; i++) {
    int idx = base + i;
    c[i] = (idx < nbc) ? bcount[idx] : 0;
    tsum += c[i];
  }
  sums[threadIdx.x] = tsum;
  __syncthreads();
  for (int off = 1; off < 256; off <<= 1) {
    int t = (threadIdx.x >= off) ? sums[threadIdx.x - off] : 0;
    __syncthreads();
    sums[threadIdx.x] += t;
    __syncthreads();
  }
  int run = sums[threadIdx.x] - tsum;
#pragma unroll
  for (int i = 0; i < SCAN_E2; i++) {
    int idx = base + i;
    if (idx < nbc) {
      bbase[idx] = run;
      bcursor[idx] = run;
    }
    run += c[i];
  }
  if (threadIdx.x == 255) {
    bbase[nbc] = sums[255];
    row_ptr[N] = nnz;
  }
}

// Per-tile: rows cached in LDS -> hist -> one global claim per (tile,bucket)
// -> ranked write. Runs of ~10 edges per bucket stay line-local to one XCD.
__global__ __launch_bounds__(256) void scatter_ranked(
    const int* __restrict__ rows, const int* __restrict__ cols,
    const float* __restrict__ vals, int* __restrict__ bcursor,
    int2* __restrict__ bucketed, int nnz, int nbc) {
  __shared__ int h[NBC_MAX];
  __shared__ int rcache[TILE_E];  // 32 KB
  int ntiles = (nnz + TILE_E - 1) / TILE_E;
  for (int tile = blockIdx.x; tile < ntiles; tile += gridDim.x) {
    int s = tile * TILE_E;
    int e = min(s + TILE_E, nnz);
    int len = e - s;
    for (int i = threadIdx.x; i < nbc; i += 256) h[i] = 0;
    for (int i = threadIdx.x; i < len; i += 256) rcache[i] = rows[s + i];
    __syncthreads();
    for (int i = threadIdx.x; i < len; i += 256)
      atomicAdd(&h[rcache[i] >> CB], 1);
    __syncthreads();
    for (int i = threadIdx.x; i < nbc; i += 256) {
      int c = h[i];
      h[i] = c ? atomicAdd(&bcursor[i], c) : 0;
    }
    __syncthreads();
    for (int i = threadIdx.x; i < len; i += 256) {
      int r = rcache[i];
      int pos = atomicAdd(&h[r >> CB], 1);
      bucketed[pos] = make_int2(cols[s + i] | ((r & (CROWS - 1)) << 20),
                                __float_as_int(vals[s + i]));
    }
    __syncthreads();
  }
}

// One block per coarse bucket: counting sort by local row (256 bins).
__global__ __launch_bounds__(256) void sort_csr(
    const int2* __restrict__ bucketed, const int* __restrict__ bbase,
    int* __restrict__ row_ptr, int* __restrict__ colsS,
    float* __restrict__ valsS, int N) {
  __shared__ int lhist[CROWS];
  __shared__ int lscan[CROWS];
  int b = blockIdx.x, t = threadIdx.x;
  int s = bbase[b], e = bbase[b + 1];
  lhist[t] = 0;
  __syncthreads();
  for (int k = s + t; k < e; k += 256)
    atomicAdd(&lhist[(unsigned)bucketed[k].x >> 20], 1);
  __syncthreads();
  int c = lhist[t];
  lscan[t] = c;
  __syncthreads();
  for (int off = 1; off < 256; off <<= 1) {
    int v = (t >= off) ? lscan[t - off] : 0;
    __syncthreads();
    lscan[t] += v;
    __syncthreads();
  }
  int excl = lscan[t] - c;
  int grow = (b << CB) + t;
  if (grow < N) row_ptr[grow] = s + excl;
  lhist[t] = s + excl;  // becomes cursor
  __syncthreads();
  for (int k = s + t; k < e; k += 256) {
    int2 g = bucketed[k];
    int lr = (unsigned)g.x >> 20;
    int dst = atomicAdd(&lhist[lr], 1);
    colsS[dst] = g.x & 0xFFFFF;
    valsS[dst] = __int_as_float(g.y);
  }
}

// ===========================================================================
// init: ego = concat(user,item); int8 quantize w/ per-row scale
// ===========================================================================
__global__ __launch_bounds__(256) void init_ego(
    const float* __restrict__ ue, const float* __restrict__ ie,
    float* __restrict__ ego, signed char* __restrict__ ego8,
    float* __restrict__ scale, int n_users, int N, int do8) {
  int wave = threadIdx.x >> 6, lane = threadIdx.x & 63;
  int n = blockIdx.x * 4 + wave;
  if (n >= N) return;
  const float* src =
      (n < n_users) ? ue + (size_t)n * D : ie + (size_t)(n - n_users) * D;
  float v = src[lane];
  ego[(size_t)n * D + lane] = v;
  if (do8) {
    float m = fabsf(v);
#pragma unroll
    for (int off = 32; off > 0; off >>= 1) m = fmaxf(m, __shfl_xor(m, off));
    m = fmaxf(m, 1e-30f);
    ego8[(size_t)n * D + lane] = (signed char)(int)rintf(v * (127.f / m));
    if (lane == 0) scale[n] = m * (1.f / 127.f);
  }
}

// per-layer: fold per-row scale into edge weights (sequential streams)
__global__ __launch_bounds__(256) void fold_svals(
    const int* __restrict__ colsS, const float* __restrict__ valsS,
    const float* __restrict__ scale, float* __restrict__ svals, int nnz) {
  int k = blockIdx.x * 256 + threadIdx.x;
  if (k < nnz) svals[k] = valsS[k] * scale[colsS[k]];
}

// ===========================================================================
// SpMM gather: wave per row, lane = feature. Edge (col,val) fetched
// lane-parallel (coalesced) and broadcast via shfl; 16 ego gathers in flight.
// ===========================================================================
template <bool FOLDED>
__global__ __launch_bounds__(256) void spmm_gather8(
    const int* __restrict__ row_ptr, const int* __restrict__ colsS,
    const float* __restrict__ valsS, const float* __restrict__ scale,
    const signed char* __restrict__ ego8, float* __restrict__ side, int N) {
  int wave = threadIdx.x >> 6, lane = threadIdx.x & 63;
  int w = blockIdx.x * 4 + wave;
  int stride = gridDim.x * 4;
  for (int n = w; n < N; n += stride) {
    int s = row_ptr[n], e = row_ptr[n + 1];
    float acc = 0.f;
    int k = s;
    while (e - k >= 16) {
      int kk = k + (lane & 15);
      int cm = colsS[kk];
      float vm = valsS[kk];
      if (!FOLDED) vm *= scale[cm];
      float x[16], vv[16];
#pragma unroll
      for (int i = 0; i < 16; i++) {
        int ci = __shfl(cm, i);
        vv[i] = __shfl(vm, i);
        x[i] = (float)ego8[(size_t)ci * D + lane];
      }
#pragma unroll
      for (int i = 0; i < 16; i++) acc = fmaf(vv[i], x[i], acc);
      k += 16;
    }
    if (e - k >= 8) {
      int kk = k + (lane & 7);
      int cm = colsS[kk];
      float vm = valsS[kk];
      if (!FOLDED) vm *= scale[cm];
      float x[8], vv[8];
#pragma unroll
      for (int i = 0; i < 8; i++) {
        int ci = __shfl(cm, i);
        vv[i] = __shfl(vm, i);
        x[i] = (float)ego8[(size_t)ci * D + lane];
      }
#pragma unroll
      for (int i = 0; i < 8; i++) acc = fmaf(vv[i], x[i], acc);
      k += 8;
    }
    for (; k < e; k++) {
      int ci = colsS[k];
      float vi = valsS[k];
      if (!FOLDED) vi *= scale[ci];
      acc = fmaf(vi, (float)ego8[(size_t)ci * D + lane], acc);
    }
    side[(size_t)n * D + lane] = acc;
  }
}

// ===========================================================================
// Fallback atomic scatter (only if ws too small / N too big for CSR path)
// ===========================================================================
__global__ __launch_bounds__(256) void scatter_spmm(
    const int* __restrict__ rows, const int* __restrict__ cols,
    const float* __restrict__ vals, const float* __restrict__ ego,
    float* __restrict__ side, int nnz) {
  long long t = (long long)blockIdx.x * blockDim.x + threadIdx.x;
  int e = (int)(t >> 4);
  if (e >= nnz) return;
  int c4 = (int)(t & 15);
  int r = rows[e];
  int c = cols[e];
  float v = vals[e];
  const float4* src = (const float4*)(ego + (size_t)c * D);
  float4 x = src[c4];
  float* dst = side + (size_t)r * D + c4 * 4;
  atomicAdd(dst + 0, v * x.x);
  atomicAdd(dst + 1, v * x.y);
  atomicAdd(dst + 2, v * x.z);
  atomicAdd(dst + 3, v * x.w);
}

// ===========================================================================
// Per-node transform; fuses int8 re-quantization of the new ego.
// ===========================================================================
__global__ __launch_bounds__(256) void transform_nodes(
    float* __restrict__ ego, const float* __restrict__ side,
    const float* __restrict__ Wgc, const float* __restrict__ bgc,
    const float* __restrict__ Wbi, const float* __restrict__ bbi,
    signed char* __restrict__ ego8, float* __restrict__ scale, int w8, int N) {
  __shared__ float sWgc[D * D];
  __shared__ float sWbi[D * D];
  __shared__ float sb[2 * D];
  __shared__ float sS[4][D];
  __shared__ float sP[4][D];

  for (int idx = threadIdx.x; idx < D * D; idx += 256) {
    sWgc[idx] = Wgc[idx];
    sWbi[idx] = Wbi[idx];
  }
  if (threadIdx.x < D) {
    sb[threadIdx.x] = bgc[threadIdx.x];
    sb[D + threadIdx.x] = bbi[threadIdx.x];
  }
  __syncthreads();

  int wave = threadIdx.x >> 6;
  int lane = threadIdx.x & 63;
  int waveGlobal = blockIdx.x * 4 + wave;
  int nWaves = gridDim.x * 4;

  for (int n = waveGlobal; n < N; n += nWaves) {
    float s = side[(size_t)n * D + lane];
    float e = ego[(size_t)n * D + lane];
    sS[wave][lane] = s;
    sP[wave][lane] = e * s;
    float accg = sb[lane];
    float accb = sb[D + lane];
#pragma unroll
    for (int i = 0; i < D; i++) {
      float si = sS[wave][i];
      float pi = sP[wave][i];
      accg = fmaf(si, sWgc[i * D + lane], accg);
      accb = fmaf(pi, sWbi[i * D + lane], accb);
    }
    float val = accg + accb;
    val = val > 0.f ? val : NEG_SLOPE * val;
    ego[(size_t)n * D + lane] = val;
    if (w8) {
      float m = fabsf(val);
#pragma unroll
      for (int off = 32; off > 0; off >>= 1) m = fmaxf(m, __shfl_xor(m, off));
      m = fmaxf(m, 1e-30f);
      ego8[(size_t)n * D + lane] = (signed char)(int)rintf(val * (127.f / m));
      if (lane == 0) scale[n] = m * (1.f / 127.f);
    }
  }
}

// ===========================================================================
// Gather one 64-wide slice of the three outputs into d_out
// ===========================================================================
__global__ __launch_bounds__(256) void gather_out(
    const float* __restrict__ ego, const int* __restrict__ u,
    const int* __restrict__ iidx, const int* __restrict__ jidx,
    float* __restrict__ out, int n_users, int B, int slice, int normalize) {
  int r = blockIdx.x * 4 + (threadIdx.x >> 6);
  int lane = threadIdx.x & 63;
  if (r >= 3 * B) return;
  int which = r / B;
  int b = r - which * B;
  int n = (which == 0) ? u[b] : (n_users + ((which == 1) ? iidx[b] : jidx[b]));
  float v = ego[(size_t)n * D + lane];
  if (normalize) {
    float sq = v * v;
#pragma unroll
    for (int off = 32; off > 0; off >>= 1) sq += __shfl_xor(sq, off);
    float norm = sqrtf(sq);
    v = v / fmaxf(norm, EPS);
  }
  out[(size_t)which * B * 256 + (size_t)b * 256 + slice * D + lane] = v;
}

// ===========================================================================
// Launch
// ===========================================================================
extern "C" void kernel_launch(void* const* d_in, const int* in_sizes, int n_in,
                              void* d_out, int out_size, void* d_ws, size_t ws_size,
                              hipStream_t stream) {
  const int*   rows     = (const int*)d_in[0];
  const int*   cols     = (const int*)d_in[1];
  const float* vals     = (const float*)d_in[2];
  const float* user_emb = (const float*)d_in[3];
  const float* item_emb = (const float*)d_in[4];
  const float* W_gc     = (const float*)d_in[5];
  const float* b_gc     = (const float*)d_in[6];
  const float* W_bi     = (const float*)d_in[7];
  const float* b_bi     = (const float*)d_in[8];
  const int*   u        = (const int*)d_in[9];
  const int*   iidx     = (const int*)d_in[10];
  const int*   jidx     = (const int*)d_in[11];

  int nnz     = in_sizes[0];
  int n_users = in_sizes[3] / D;
  int n_items = in_sizes[4] / D;
  int N       = n_users + n_items;
  int B       = in_sizes[9];
  float* out  = (float*)d_out;

  int nbc = (N + CROWS - 1) >> CB;

  // ---- workspace layout ----
  auto align256 = [](size_t x) { return (x + 255) & ~(size_t)255; };
  char* p = (char*)d_ws;
  size_t egoBytes  = align256((size_t)N * D * sizeof(float));
  size_t sideBytes = align256((size_t)N * D * sizeof(float));
  if ((size_t)nnz * sizeof(int2) > sideBytes)
    sideBytes = align256((size_t)nnz * sizeof(int2));  // bucketed aliases side

  float* ego  = (float*)p; p += egoBytes;
  float* side = (float*)p;
  int2* bucketed = (int2*)side;  // alias: dead before first spmm use of side
  p += sideBytes;
  int* row_ptr = (int*)p; p += align256((size_t)(N + 1) * sizeof(int));
  int* bcount  = (int*)p; p += align256((size_t)(nbc + 1) * sizeof(int));
  int* bbase   = (int*)p; p += align256((size_t)(nbc + 1) * sizeof(int));
  int* bcursor = (int*)p; p += align256((size_t)(nbc + 1) * sizeof(int));
  int*   colsS = (int*)p;   p += align256((size_t)nnz * sizeof(int));
  float* valsS = (float*)p; p += align256((size_t)nnz * sizeof(float));
  signed char* ego8 = (signed char*)p; p += align256((size_t)N * D);
  float* scale = (float*)p; p += align256((size_t)N * sizeof(float));
  size_t need_base = (size_t)(p - (char*)d_ws);
  float* svals = (float*)p; p += align256((size_t)nnz * sizeof(float));
  size_t need_fold = (size_t)(p - (char*)d_ws);

  int mode = (ws_size >= need_base && N <= (1 << 20) && nbc <= NBC_MAX) ? 0 : 2;
  int folded = (mode == 0 && ws_size >= need_fold) ? 1 : 0;

  init_ego<<<(N + 3) / 4, 256, 0, stream>>>(user_emb, item_emb, ego, ego8,
                                            scale, n_users, N, mode == 0);

  if (mode == 0) {
    hipMemsetAsync(bcount, 0, (size_t)nbc * sizeof(int), stream);
    hist_coarse<<<256, 256, 0, stream>>>(rows, bcount, nnz, nbc);
    scan_buckets<<<1, 256, 0, stream>>>(bcount, bbase, bcursor, nbc, nnz,
                                        row_ptr, N);
    int ntiles = (nnz + TILE_E - 1) / TILE_E;
    scatter_ranked<<<ntiles, 256, 0, stream>>>(rows, cols, vals, bcursor,
                                               bucketed, nnz, nbc);
    sort_csr<<<nbc, 256, 0, stream>>>(bucketed, bbase, row_ptr, colsS, valsS,
                                      N);
  }

  // slice 0: raw embeddings
  int gblocks = (3 * B + 3) / 4;
  gather_out<<<gblocks, 256, 0, stream>>>(ego, u, iidx, jidx, out, n_users, B,
                                          0, 0);

  long long sthreads = (long long)nnz * 16;
  int sblocks = (int)((sthreads + 255) / 256);
  int eblocks = (nnz + 255) / 256;

  for (int k = 0; k < 3; k++) {
    if (mode == 0) {
      if (folded) {
        fold_svals<<<eblocks, 256, 0, stream>>>(colsS, valsS, scale, svals,
                                                nnz);
        spmm_gather8<true><<<2048, 256, 0, stream>>>(row_ptr, colsS, svals,
                                                     nullptr, ego8, side, N);
      } else {
        spmm_gather8<false><<<2048, 256, 0, stream>>>(row_ptr, colsS, valsS,
                                                      scale, ego8, side, N);
      }
    } else {
      hipMemsetAsync(side, 0, (size_t)N * D * sizeof(float), stream);
      scatter_spmm<<<sblocks, 256, 0, stream>>>(rows, cols, vals, ego, side,
                                                nnz);
    }
    transform_nodes<<<2048, 256, 0, stream>>>(
        ego, side, W_gc + (size_t)k * D * D, b_gc + (size_t)k * D,
        W_bi + (size_t)k * D * D, b_bi + (size_t)k * D, ego8, scale, mode == 0,
        N);
    gather_out<<<gblocks, 256, 0, stream>>>(ego, u, iidx, jidx, out, n_users,
                                            B, k + 1, 1);
  }
}